// Round 8
// baseline (399.900 us; speedup 1.0000x reference)
//
#include <hip/hip_runtime.h>
#include <hip/hip_bf16.h>

#define N_NODES 50000
#define NIN 128
#define NOUT 64
#define EIN 32
#define N_EDGES 400000
#define N_UNITS (2 * N_EDGES)
#define ALPHA 0.2f
#define NBINS 16

__device__ __forceinline__ int clampi(int x) {
  return min(max(x, 0), N_NODES - 1);
}

// ---------------------------------------------------------------------------
// Kernel 1: h = node_fts @ W + b (f32), fused A = h.a1, B = h.a2, hn = ||h||.
// One wave per node, lane j = column j.
// ---------------------------------------------------------------------------
__global__ __launch_bounds__(256) void k_gemm(
    const float* __restrict__ nf, const float* __restrict__ W,
    const float* __restrict__ b, const float* __restrict__ a,
    float* __restrict__ h, float* __restrict__ A, float* __restrict__ B,
    float* __restrict__ hn) {
  __shared__ float Ws[NIN * NOUT];  // 32 KB
  __shared__ float bs[NOUT], a1s[NOUT], a2s[NOUT];
  __shared__ float rows[4][NIN];
  int t = threadIdx.x;
#pragma unroll
  for (int n = 0; n < 32; ++n) Ws[t + n * 256] = W[t + n * 256];
  if (t < 64) { bs[t] = b[t]; a1s[t] = a[t]; a2s[t] = a[64 + t]; }
  __syncthreads();
  int j = t & 63, local = t >> 6;
  for (int v0 = blockIdx.x * 4; v0 < N_NODES; v0 += gridDim.x * 4) {
    int vload = v0 + (t >> 6);
    if (vload < N_NODES) {
      float2 p = ((const float2*)(nf + (size_t)vload * NIN))[t & 63];
      ((float2*)rows[t >> 6])[t & 63] = p;
    }
    __syncthreads();
    int v = v0 + local;
    if (v < N_NODES) {
      float acc = bs[j];
      const float* r = rows[local];
#pragma unroll
      for (int k = 0; k < NIN; k += 4) {
        float4 rk = *(const float4*)&r[k];
        acc += rk.x * Ws[(k + 0) * NOUT + j];
        acc += rk.y * Ws[(k + 1) * NOUT + j];
        acc += rk.z * Ws[(k + 2) * NOUT + j];
        acc += rk.w * Ws[(k + 3) * NOUT + j];
      }
      h[(size_t)v * NOUT + j] = acc;
      float pa = acc * a1s[j], pb = acc * a2s[j], pn = acc * acc;
      for (int o = 32; o > 0; o >>= 1) {
        pa += __shfl_down(pa, o, 64);
        pb += __shfl_down(pb, o, 64);
        pn += __shfl_down(pn, o, 64);
      }
      if (j == 0) { A[v] = pa; B[v] = pb; hn[v] = sqrtf(pn); }
    }
    __syncthreads();
  }
}

// ---------------------------------------------------------------------------
// Kernel 2: per edge: lrelu logits both directions -> l[]; rank via count
// atomic (the ONLY atomic left on the edge path).
// ---------------------------------------------------------------------------
__global__ __launch_bounds__(256) void k_edge1(
    const int* __restrict__ eb, const float* __restrict__ ef,
    const float* __restrict__ a, const float* __restrict__ A,
    const float* __restrict__ B, float* __restrict__ l,
    int* __restrict__ rank, int* __restrict__ count) {
  __shared__ float a3s[EIN];
  if (threadIdx.x < EIN) a3s[threadIdx.x] = a[128 + threadIdx.x];
  __syncthreads();
  int i = blockIdx.x * blockDim.x + threadIdx.x;
  if (i >= N_EDGES) return;
  int2 sd = ((const int2*)eb)[i];
  int s = clampi(sd.x), d = clampi(sd.y);
  const float4* efp = (const float4*)(ef + (size_t)i * EIN);
  float c = 0.f;
#pragma unroll
  for (int q = 0; q < 8; ++q) {
    float4 u = efp[q];
    c += u.x * a3s[4 * q + 0] + u.y * a3s[4 * q + 1] +
         u.z * a3s[4 * q + 2] + u.w * a3s[4 * q + 3];
  }
  float zf = A[s] + B[d] + c;  // forward: src=s, dst=d
  float zr = A[d] + B[s] + c;  // reverse: src=d, dst=s
  l[i] = zf > 0.f ? zf : ALPHA * zf;
  l[N_EDGES + i] = zr > 0.f ? zr : ALPHA * zr;
  rank[i] = atomicAdd(&count[s], 1);
  rank[N_EDGES + i] = atomicAdd(&count[d], 1);
}

// ---------------------------------------------------------------------------
// Kernel 3: single-block exclusive scan of count[50000] -> off.
// ---------------------------------------------------------------------------
__global__ __launch_bounds__(1024) void k_scan(const int* __restrict__ count,
                                               int* __restrict__ off) {
  __shared__ int ls[1024];
  int t = threadIdx.x;
  const int CH = 49;  // ceil(50000/1024)
  int start = t * CH, end = min(start + CH, N_NODES);
  int s = 0;
  for (int i = start; i < end; ++i) s += count[i];
  ls[t] = s;
  __syncthreads();
  for (int o = 1; o < 1024; o <<= 1) {
    int v = (t >= o) ? ls[t - o] : 0;
    __syncthreads();
    ls[t] += v;
    __syncthreads();
  }
  int run = (t == 0) ? 0 : ls[t - 1];
  for (int i = start; i < end; ++i) {
    off[i] = run;
    run += count[i];
  }
  if (t == 1023) off[N_NODES] = ls[1023];
}

// ---------------------------------------------------------------------------
// Kernel 4: pure scatter: csr[off[s]+rank[u]] = (dst, logit). No atomics,
// no transcendentals.
// ---------------------------------------------------------------------------
__global__ __launch_bounds__(256) void k_edge2(
    const int* __restrict__ eb, const float* __restrict__ l,
    const int* __restrict__ rank, const int* __restrict__ off,
    int2* __restrict__ csr) {
  int u = blockIdx.x * blockDim.x + threadIdx.x;
  if (u >= N_UNITS) return;
  int s, d;
  if (u < N_EDGES) {
    int2 sd = ((const int2*)eb)[u];
    s = sd.x; d = sd.y;
  } else {
    int2 sd = ((const int2*)eb)[u - N_EDGES];
    s = sd.y; d = sd.x;
  }
  s = clampi(s);
  d = clampi(d);
  csr[off[s] + rank[u]] = make_int2(d, __float_as_int(l[u]));
}

// ---------------------------------------------------------------------------
// Kernel 5: one wave per node, two passes over its CSR segment.
// Pass 1: sumexp, sum_l, sum_l2 (lane-parallel, xor-reduce) -> lse.
// Pass 2: msg_j = sum_k h[dst_k][j]*(l_k - lse)  (first chunk register-cached).
// Variance contribution per node in closed form; block LDS reduce -> binned
// f64 atomics. Output row v = f32 [h_v | agg_v].
// ---------------------------------------------------------------------------
__global__ __launch_bounds__(256) void k_gather(
    const float* __restrict__ h, const float* __restrict__ hn,
    const int* __restrict__ off, const int2* __restrict__ csr,
    const float* __restrict__ scale_p, float* __restrict__ out,
    double* __restrict__ sums) {
  __shared__ double ws1[4], ws2[4];
  float scale = scale_p[0];
  int j = threadIdx.x & 63;
  int wave = threadIdx.x >> 6;
  int v = blockIdx.x * 4 + wave;
  double myS1 = 0.0, myS2 = 0.0;
  if (v < N_NODES) {
    int k0 = off[v], k1 = off[v + 1];
    int len = k1 - k0;
    // ---- pass 1 ----
    float sumexp = 0.f, sl = 0.f, sl2 = 0.f;
    int idx0 = 0;
    float l0 = 0.f;
    for (int kb = k0; kb < k1; kb += 64) {
      int nk = min(64, k1 - kb);
      int idx = 0;
      float lv = 0.f;
      if (j < nk) {
        int2 e = csr[kb + j];
        idx = e.x;
        lv = __int_as_float(e.y);
        sumexp += expf(lv);
        sl += lv;
        sl2 += lv * lv;
      }
      if (kb == k0) { idx0 = idx; l0 = lv; }
    }
    for (int o = 32; o > 0; o >>= 1) {
      sumexp += __shfl_xor(sumexp, o, 64);
      sl += __shfl_xor(sl, o, 64);
      sl2 += __shfl_xor(sl2, o, 64);
    }
    float lse = logf(sumexp);
    // ---- pass 2 ----
    float msg = 0.f;
    for (int kb = k0; kb < k1; kb += 64) {
      int nk = min(64, k1 - kb);
      int idx;
      float lv;
      if (kb == k0) {
        idx = idx0;
        lv = l0;
      } else {
        idx = 0;
        lv = 0.f;
        if (j < nk) {
          int2 e = csr[kb + j];
          idx = e.x;
          lv = __int_as_float(e.y);
        }
      }
      for (int kk = 0; kk < nk; ++kk) {
        int dk = __shfl(idx, kk, 64);
        float ak = __shfl(lv, kk, 64) - lse;
        msg += h[(size_t)dk * NOUT + j] * ak;
      }
    }
    float nrm = msg * msg;
    for (int o = 32; o > 0; o >>= 1) nrm += __shfl_xor(nrm, o, 64);
    nrm = sqrtf(nrm);
    float fac = hn[v] * scale / fmaxf(nrm, 1e-12f);
    out[(size_t)v * 128 + j] = h[(size_t)v * NOUT + j];
    out[(size_t)v * 128 + 64 + j] = msg * fac;
    if (len > 0) {
      myS1 = (double)sl - (double)len * (double)lse;
      myS2 = (double)sl2 - 2.0 * (double)lse * (double)sl +
             (double)len * (double)lse * (double)lse;
    }
  }
  if (j == 0) { ws1[wave] = myS1; ws2[wave] = myS2; }
  __syncthreads();
  if (threadIdx.x == 0) {
    double t1 = ws1[0] + ws1[1] + ws1[2] + ws1[3];
    double t2 = ws2[0] + ws2[1] + ws2[2] + ws2[3];
    int bin = blockIdx.x & (NBINS - 1);
    atomicAdd(&sums[2 * bin], t1);
    atomicAdd(&sums[2 * bin + 1], t2);
  }
}

// ---------------------------------------------------------------------------
// Kernel 6: reduce 16 bins -> att_var -> out[6,400,000] (f32)
// ---------------------------------------------------------------------------
__global__ void k_var(const double* __restrict__ sums,
                      float* __restrict__ out) {
  if (threadIdx.x == 0 && blockIdx.x == 0) {
    double S1 = 0.0, S2 = 0.0;
#pragma unroll
    for (int i = 0; i < NBINS; ++i) {
      S1 += sums[2 * i];
      S2 += sums[2 * i + 1];
    }
    double M = (double)N_UNITS;
    double var = (S2 - S1 * S1 / M) / (M - 1.0);
    out[(size_t)N_NODES * 128] = (float)var;
  }
}

extern "C" void kernel_launch(void* const* d_in, const int* in_sizes, int n_in,
                              void* d_out, int out_size, void* d_ws,
                              size_t ws_size, hipStream_t stream) {
  const float* nf = (const float*)d_in[0];
  const float* ef = (const float*)d_in[1];
  const int* eb = (const int*)d_in[2];
  const float* W = (const float*)d_in[3];
  const float* b = (const float*)d_in[4];
  const float* a = (const float*)d_in[5];
  const float* scale_p = (const float*)d_in[6];
  float* out = (float*)d_out;  // 6,400,001 f32

  char* ws = (char*)d_ws;
  float* h = (float*)(ws + 0);              // 12,800,000 B
  float* l = (float*)(ws + 12800000);       //  3,200,000 B
  int* rank = (int*)(ws + 16000000);        //  3,200,000 B
  int2* csr = (int2*)(ws + 19200000);       //  6,400,000 B
  float* A = (float*)(ws + 25600000);       //    200,000 B
  float* B = (float*)(ws + 25800000);       //    200,000 B
  float* hn = (float*)(ws + 26000000);      //    200,000 B
  int* off = (int*)(ws + 26200000);         //    200,016 B (50001 + pad)
  int* count = (int*)(ws + 26400016);       //    200,000 B
  double* sums = (double*)(ws + 26600016);  //        256 B (16 bins x 2)

  // zero count + sums (contiguous)
  hipMemsetAsync(ws + 26400016, 0, 200256, stream);

  k_gemm<<<1024, 256, 0, stream>>>(nf, W, b, a, h, A, B, hn);
  k_edge1<<<(N_EDGES + 255) / 256, 256, 0, stream>>>(eb, ef, a, A, B, l, rank,
                                                     count);
  k_scan<<<1, 1024, 0, stream>>>(count, off);
  k_edge2<<<(N_UNITS + 255) / 256, 256, 0, stream>>>(eb, l, rank, off, csr);
  k_gather<<<12500, 256, 0, stream>>>(h, hn, off, csr, scale_p, out, sums);
  k_var<<<1, 64, 0, stream>>>(sums, out);
}